// Round 1
// baseline (29.761 us; speedup 1.0000x reference)
//
#include <hip/hip_runtime.h>

#define ORDER 64

// Fast path: one block per d-channel; 256 threads; each thread owns
// l = tid + 256*j for j in [0,J). Geometric recurrence along l:
//   s_o(l + 256) = s_o(l) * exp(256 * g_o)
// Pair trick: per j-pair, 3 ops per order instead of 4:
//   acc[j]   += q_o                 (q_o = R_o * exp(g_o * l))
//   acc[j+1] += q_o * w_o           (fma, w_o = exp(256 g_o))
//   q_o      *= w_o^2               (advance 512)
template <int J>
__global__ __launch_bounds__(256) void imf_fast(const float* __restrict__ gamma,
                                                const float* __restrict__ R,
                                                const float* __restrict__ p,
                                                float* __restrict__ out,
                                                int L) {
    const int d = blockIdx.x;
    const int tid = threadIdx.x;

    __shared__ float sh_g[ORDER];
    __shared__ float sh_w[ORDER];
    __shared__ float sh_w2[ORDER];
    __shared__ float sh_R[ORDER];

    if (tid < ORDER) {
        const int idx = d * ORDER + tid;
        // glogp = -exp(p) * exp(gamma), matching the reference elementwise form
        const float gl = -__expf(p[idx]) * __expf(gamma[idx]);
        const float w = __expf(gl * 256.0f);
        sh_g[tid] = gl;
        sh_w[tid] = w;
        sh_w2[tid] = w * w;
        sh_R[tid] = R[idx];
    }
    __syncthreads();

    const float lbase = (float)tid;

    float acc[J];
#pragma unroll
    for (int j = 0; j < J; ++j) acc[j] = 0.0f;

    // 4 groups of 16 orders; keep the group loop rolled so only one
    // group's {q,w,w2} is live at a time (~64 core VGPRs).
#pragma unroll 1
    for (int g = 0; g < ORDER / 16; ++g) {
        float q[16], w[16], w2[16];
#pragma unroll
        for (int i = 0; i < 16; ++i) {
            const int o = g * 16 + i;
            const float gl = sh_g[o];
            q[i] = sh_R[o] * __expf(gl * lbase);
            w[i] = sh_w[o];
            w2[i] = sh_w2[o];
        }
#pragma unroll
        for (int j = 0; j < J; j += 2) {
#pragma unroll
            for (int i = 0; i < 16; ++i) {
                acc[j] += q[i];
                acc[j + 1] = fmaf(q[i], w[i], acc[j + 1]);
                q[i] *= w2[i];
            }
        }
    }

    float* o_ptr = out + (size_t)d * L + tid;
#pragma unroll
    for (int j = 0; j < J; ++j) o_ptr[j * 256] = acc[j];
}

// Generic fallback for any L: one thread per (d, l), direct exp evaluation.
__global__ void imf_generic(const float* __restrict__ gamma,
                            const float* __restrict__ R,
                            const float* __restrict__ p,
                            float* __restrict__ out,
                            int D, int L) {
    const int idx = blockIdx.x * blockDim.x + threadIdx.x;
    const int total = D * L;
    if (idx >= total) return;
    const int d = idx / L;
    const int l = idx - d * L;
    const float lf = (float)l;
    float acc = 0.0f;
    for (int o = 0; o < ORDER; ++o) {
        const int k = d * ORDER + o;
        const float gl = -__expf(p[k]) * __expf(gamma[k]);
        acc = fmaf(R[k], __expf(gl * lf), acc);
    }
    out[idx] = acc;
}

extern "C" void kernel_launch(void* const* d_in, const int* in_sizes, int n_in,
                              void* d_out, int out_size, void* d_ws, size_t ws_size,
                              hipStream_t stream) {
    // inputs: [0]=L (scalar int, unused — derived from sizes), [1]=gamma, [2]=R, [3]=p
    const float* gamma = (const float*)d_in[1];
    const float* R = (const float*)d_in[2];
    const float* p = (const float*)d_in[3];
    float* out = (float*)d_out;

    const int D = in_sizes[1] / ORDER;   // 2048
    const int L = out_size / D;          // 4096

    if (L == 4096) {
        imf_fast<16><<<dim3(D), dim3(256), 0, stream>>>(gamma, R, p, out, L);
    } else {
        const int total = D * L;
        imf_generic<<<dim3((total + 255) / 256), dim3(256), 0, stream>>>(gamma, R, p, out, D, L);
    }
}

// Round 3
// 13.189 us; speedup vs baseline: 2.2565x; 2.2565x over previous
//
#include <hip/hip_runtime.h>

#define ORDER 64

typedef _Float16 half8 __attribute__((ext_vector_type(8)));
typedef __fp16 fp16x2 __attribute__((ext_vector_type(2)));
typedef float floatx4 __attribute__((ext_vector_type(4)));

// MFMA formulation. For each channel d:
//   h[16*l0 + i] = sum_o Q[l0,o] * W[o,i],  Q[l0,o] = R_o*exp(g_o*16*l0),
//   W[o,i] = exp(g_o*i),  g = -exp(p+gamma)
// -> per d: (256 x 64) @ (64 x 16) matmul, tiled as 16 MFMAs of 16x16x32 (x2 K-steps).
// Fragments are generated in-register (no LDS): A-row m = lane&15,
// k-slice o = 32h + 8*(lane>>4) + j. Any k-permutation assumption cancels since
// A and B use the same (lane,j)->o map. Q advances across consecutive tiles by
// one v_mul per element (geometric recurrence), exp only at init.
// Block = 256 threads = 4 waves; waves (0,1)->d0 tiles [0..8),[8..16),
// waves (2,3)->d1. Grid = D/2.
__global__ __launch_bounds__(256) void imf_mfma(const float* __restrict__ gamma,
                                                const float* __restrict__ R,
                                                const float* __restrict__ p,
                                                float* __restrict__ out) {
    const int tid  = threadIdx.x;
    const int wave = tid >> 6;
    const int lane = tid & 63;
    const int c15  = lane & 15;   // A-row m / B-col i / C-col
    const int g16  = lane >> 4;   // 0..3

    const int d     = blockIdx.x * 2 + (wave >> 1);
    const int tile0 = (wave & 1) * 8;

    float wstep[2][8];   // exp(g*256): Q advance per 16-l0 tile
    float q[2][8];       // current Q (f32, converted to f16 per tile)
    half8 B[2];

    const float fc  = (float)c15;
    const float Lr0 = (float)(256 * tile0 + 16 * c15);

#pragma unroll
    for (int h = 0; h < 2; ++h) {
        const int obase = d * ORDER + 32 * h + 8 * g16;
        const float* gp = gamma + obase;
        const float* pp = p + obase;
        const float* rp = R + obase;
        float glp[8];
#pragma unroll
        for (int j = 0; j < 8; ++j) {
            const float g = -__expf(gp[j] + pp[j]);   // glogp = -exp(p)*exp(gamma)
            glp[j]      = g;
            wstep[h][j] = __expf(g * 256.0f);
            q[h][j]     = rp[j] * __expf(g * Lr0);
        }
        // B fragment: W[o, i=c15]
#pragma unroll
        for (int j = 0; j < 8; ++j) {
            B[h][j] = (_Float16)__expf(glp[j] * fc);
        }
    }

    float* op = out + ((size_t)d << 12) + (size_t)tile0 * 256 + 64 * g16 + c15;

#pragma unroll
    for (int t = 0; t < 8; ++t) {
        half8 A0, A1;
#pragma unroll
        for (int j = 0; j < 8; j += 2) {
            fp16x2 p0 = __builtin_amdgcn_cvt_pkrtz(q[0][j], q[0][j + 1]);
            A0[j]     = (_Float16)p0[0];
            A0[j + 1] = (_Float16)p0[1];
            fp16x2 p1 = __builtin_amdgcn_cvt_pkrtz(q[1][j], q[1][j + 1]);
            A1[j]     = (_Float16)p1[0];
            A1[j + 1] = (_Float16)p1[1];
        }
        floatx4 acc = {0.f, 0.f, 0.f, 0.f};
        acc = __builtin_amdgcn_mfma_f32_16x16x32_f16(A0, B[0], acc, 0, 0, 0);
        acc = __builtin_amdgcn_mfma_f32_16x16x32_f16(A1, B[1], acc, 0, 0, 0);
        // advance Q to next tile (independent of mfma result -> overlaps)
#pragma unroll
        for (int j = 0; j < 8; ++j) {
            q[0][j] *= wstep[0][j];
            q[1][j] *= wstep[1][j];
        }
        // C layout (verified): col = lane&15, row = 4*(lane>>4) + reg
        op[0]  = acc[0];
        op[16] = acc[1];
        op[32] = acc[2];
        op[48] = acc[3];
        op += 256;
    }
}

// Generic fallback for any L: one thread per (d, l), direct exp evaluation.
__global__ void imf_generic(const float* __restrict__ gamma,
                            const float* __restrict__ R,
                            const float* __restrict__ p,
                            float* __restrict__ out,
                            int D, int L) {
    const int idx = blockIdx.x * blockDim.x + threadIdx.x;
    const int total = D * L;
    if (idx >= total) return;
    const int d = idx / L;
    const int l = idx - d * L;
    const float lf = (float)l;
    float acc = 0.0f;
    for (int o = 0; o < ORDER; ++o) {
        const int k = d * ORDER + o;
        const float gl = -__expf(p[k] + gamma[k]);
        acc = fmaf(R[k], __expf(gl * lf), acc);
    }
    out[idx] = acc;
}

extern "C" void kernel_launch(void* const* d_in, const int* in_sizes, int n_in,
                              void* d_out, int out_size, void* d_ws, size_t ws_size,
                              hipStream_t stream) {
    // inputs: [0]=L (scalar), [1]=gamma, [2]=R, [3]=p
    const float* gamma = (const float*)d_in[1];
    const float* R = (const float*)d_in[2];
    const float* p = (const float*)d_in[3];
    float* out = (float*)d_out;

    const int D = in_sizes[1] / ORDER;   // 2048
    const int L = out_size / D;          // 4096

    if (L == 4096 && (D & 1) == 0) {
        imf_mfma<<<dim3(D / 2), dim3(256), 0, stream>>>(gamma, R, p, out);
    } else {
        const int total = D * L;
        imf_generic<<<dim3((total + 255) / 256), dim3(256), 0, stream>>>(gamma, R, p, out, D, L);
    }
}

// Round 4
// 13.016 us; speedup vs baseline: 2.2866x; 1.0133x over previous
//
#include <hip/hip_runtime.h>

#define ORDER 64

typedef _Float16 half8 __attribute__((ext_vector_type(8)));
typedef __fp16 fp16x2 __attribute__((ext_vector_type(2)));
typedef float floatx4 __attribute__((ext_vector_type(4)));

// MFMA formulation, operand-swapped for vectorized stores.
// For each channel d:  h[16*l0 + i] = sum_o W[i,o] * Q[l0,o]
//   Q[l0,o] = R_o*exp(g_o*16*l0),  W[i,o] = exp(g_o*i),  g = -exp(p+gamma)
// MFMA computes C2[m=i, n=l0] = sum_k A[m,k]B[k,n] with A=W (constant
// across tiles), B=Q (geometric recurrence). C/D layout: col=lane&15,
// row=4*(lane>>4)+reg  =>  lane holds h[256*T + 16*c15 + 4*g16 + {0..3}]
// — 4 CONSECUTIVE l values => one global_store_dwordx4 per tile.
// Fragments generated in-register (no LDS); A and B use the same
// (g16,j)->o map so any k-permutation assumption cancels.
// Block = 256 threads = 4 waves; waves (0,1)->d0 tiles [0..8),[8..16),
// waves (2,3)->d1. Grid = D/2.
__global__ __launch_bounds__(256) void imf_mfma(const float* __restrict__ gamma,
                                                const float* __restrict__ R,
                                                const float* __restrict__ p,
                                                float* __restrict__ out) {
    const int tid  = threadIdx.x;
    const int wave = tid >> 6;
    const int lane = tid & 63;
    const int c15  = lane & 15;   // A-row i / B-col l0 / C-col
    const int g16  = lane >> 4;   // 0..3

    const int d     = blockIdx.x * 2 + (wave >> 1);
    const int tile0 = (wave & 1) * 8;

    float wstep[2][8];   // exp(g*256): Q advance per 16-l0 tile
    float q[2][8];       // current Q (f32, converted to f16 per tile)
    half8 Wf[2];         // A operand: W[i=c15, o-slice] (constant)

    const float fc  = (float)c15;
    const float Lr0 = (float)(256 * tile0 + 16 * c15);

#pragma unroll
    for (int h = 0; h < 2; ++h) {
        const int obase = d * ORDER + 32 * h + 8 * g16;
        const float* gp = gamma + obase;
        const float* pp = p + obase;
        const float* rp = R + obase;
        float glp[8];
#pragma unroll
        for (int j = 0; j < 8; ++j) {
            const float g = -__expf(gp[j] + pp[j]);   // glogp = -exp(p)*exp(gamma)
            glp[j]      = g;
            wstep[h][j] = __expf(g * 256.0f);
            q[h][j]     = rp[j] * __expf(g * Lr0);
        }
#pragma unroll
        for (int j = 0; j < 8; ++j) {
            Wf[h][j] = (_Float16)__expf(glp[j] * fc);
        }
    }

    // element offset: d*4096 + 256*tile0 + 16*c15 + 4*g16  (16B aligned)
    floatx4* op4 = (floatx4*)(out + ((size_t)d << 12) + 256 * tile0 + 16 * c15 + 4 * g16);

#pragma unroll
    for (int t = 0; t < 8; ++t) {
        half8 Q0, Q1;
#pragma unroll
        for (int j = 0; j < 8; j += 2) {
            fp16x2 p0 = __builtin_amdgcn_cvt_pkrtz(q[0][j], q[0][j + 1]);
            Q0[j]     = (_Float16)p0[0];
            Q0[j + 1] = (_Float16)p0[1];
            fp16x2 p1 = __builtin_amdgcn_cvt_pkrtz(q[1][j], q[1][j + 1]);
            Q1[j]     = (_Float16)p1[0];
            Q1[j + 1] = (_Float16)p1[1];
        }
        floatx4 acc = {0.f, 0.f, 0.f, 0.f};
        acc = __builtin_amdgcn_mfma_f32_16x16x32_f16(Wf[0], Q0, acc, 0, 0, 0);
        acc = __builtin_amdgcn_mfma_f32_16x16x32_f16(Wf[1], Q1, acc, 0, 0, 0);
        // advance Q to next tile (independent of mfma result -> overlaps)
#pragma unroll
        for (int j = 0; j < 8; ++j) {
            q[0][j] *= wstep[0][j];
            q[1][j] *= wstep[1][j];
        }
        op4[t * 64] = acc;   // 256 floats per tile step
    }
}

// Generic fallback for any L: one thread per (d, l), direct exp evaluation.
__global__ void imf_generic(const float* __restrict__ gamma,
                            const float* __restrict__ R,
                            const float* __restrict__ p,
                            float* __restrict__ out,
                            int D, int L) {
    const int idx = blockIdx.x * blockDim.x + threadIdx.x;
    const int total = D * L;
    if (idx >= total) return;
    const int d = idx / L;
    const int l = idx - d * L;
    const float lf = (float)l;
    float acc = 0.0f;
    for (int o = 0; o < ORDER; ++o) {
        const int k = d * ORDER + o;
        const float gl = -__expf(p[k] + gamma[k]);
        acc = fmaf(R[k], __expf(gl * lf), acc);
    }
    out[idx] = acc;
}

extern "C" void kernel_launch(void* const* d_in, const int* in_sizes, int n_in,
                              void* d_out, int out_size, void* d_ws, size_t ws_size,
                              hipStream_t stream) {
    // inputs: [0]=L (scalar), [1]=gamma, [2]=R, [3]=p
    const float* gamma = (const float*)d_in[1];
    const float* R = (const float*)d_in[2];
    const float* p = (const float*)d_in[3];
    float* out = (float*)d_out;

    const int D = in_sizes[1] / ORDER;   // 2048
    const int L = out_size / D;          // 4096

    if (L == 4096 && (D & 1) == 0) {
        imf_mfma<<<dim3(D / 2), dim3(256), 0, stream>>>(gamma, R, p, out);
    } else {
        const int total = D * L;
        imf_generic<<<dim3((total + 255) / 256), dim3(256), 0, stream>>>(gamma, R, p, out, D, L);
    }
}